// Round 2
// baseline (1312.436 us; speedup 1.0000x reference)
//
#include <hip/hip_runtime.h>
#include <math.h>

#define S_N 3000
#define NCHUNK 16
#define CHUNK_COLS 1875   // 30000 / 16
#define PANEL 128

__device__ __forceinline__ float sigm(float x) { return 1.0f / (1.0f + expf(-x)); }

__device__ __forceinline__ void ins_stream(float (&v)[5], int (&ix)[5],
                                           float nv, int ni) {
  // candidates arrive in ascending index order -> strict > == lax.top_k tie rule
  if (nv > v[4]) {
    if (nv > v[3]) { v[4] = v[3]; ix[4] = ix[3];
      if (nv > v[2]) { v[3] = v[2]; ix[3] = ix[2];
        if (nv > v[1]) { v[2] = v[1]; ix[2] = ix[1];
          if (nv > v[0]) { v[1] = v[0]; ix[1] = ix[0]; v[0] = nv; ix[0] = ni; }
          else { v[1] = nv; ix[1] = ni; }
        } else { v[2] = nv; ix[2] = ni; }
      } else { v[3] = nv; ix[3] = ni; }
    } else { v[4] = nv; ix[4] = ni; }
  }
}

__device__ __forceinline__ bool bet(float av, int ai, float bv, int bi) {
  return (av > bv) || (av == bv && ai < bi);
}

__device__ __forceinline__ void ins_full(float (&v)[5], int (&ix)[5],
                                         float nv, int ni) {
  if (bet(nv, ni, v[4], ix[4])) {
    if (bet(nv, ni, v[3], ix[3])) { v[4] = v[3]; ix[4] = ix[3];
      if (bet(nv, ni, v[2], ix[2])) { v[3] = v[2]; ix[3] = ix[2];
        if (bet(nv, ni, v[1], ix[1])) { v[2] = v[1]; ix[2] = ix[1];
          if (bet(nv, ni, v[0], ix[0])) { v[1] = v[0]; ix[1] = ix[0]; v[0] = nv; ix[0] = ni; }
          else { v[1] = nv; ix[1] = ni; }
        } else { v[2] = nv; ix[2] = ni; }
      } else { v[3] = nv; ix[3] = ni; }
    } else { v[4] = nv; ix[4] = ni; }
  }
}

// ---------------------------------------------------------------------------
// Kernel 1: LSTM. 250 blocks x 1024 threads; each block owns 12 sequences.
// Each lane holds Whh[j][kh*64 .. kh*64+63] stationary in 64 VGPRs.
// ---------------------------------------------------------------------------
__global__ __launch_bounds__(1024, 4) void lstm_kernel(
    const float* __restrict__ Xs, const float* __restrict__ Wih,
    const float* __restrict__ Whh, const float* __restrict__ bih,
    const float* __restrict__ bhh, float* __restrict__ H10)
{
  __shared__ float h_s[12 * 128];       // 6 KB
  __shared__ float P[2 * 12 * 512];     // 48 KB
  const int tid = threadIdx.x;
  const int s0 = blockIdx.x * 12;

  for (int i = tid; i < 12 * 128; i += 1024) h_s[i] = 0.0f;

  const int lane = tid & 63;
  const int wv = tid >> 6;
  const int j = (wv & 7) * 64 + lane;
  const int kh = wv >> 3;

  float4 w4[16];
  {
    const float4* wr = (const float4*)(Whh + j * 128 + kh * 64);
#pragma unroll
    for (int q = 0; q < 16; q++) w4[q] = wr[q];
  }
  float wi0 = 0, wi1 = 0, wi2 = 0, wi3 = 0, wi4 = 0, wi5 = 0, bj = 0;
  if (kh == 0) {
    wi0 = Wih[j * 6 + 0]; wi1 = Wih[j * 6 + 1]; wi2 = Wih[j * 6 + 2];
    wi3 = Wih[j * 6 + 3]; wi4 = Wih[j * 6 + 4]; wi5 = Wih[j * 6 + 5];
    bj = bih[j] + bhh[j];
  }

  float c0 = 0.0f, c1 = 0.0f;
  const int p0m = tid >> 7;      // 0..7
  const int pn = tid & 127;

  __syncthreads();

  for (int t = 0; t < 40; t++) {
    // ---- phase 1: gate pre-activations ----
#pragma unroll 1
    for (int m = 0; m < 12; m++) {
      float acc;
      if (kh == 0) {
        const float* xm = Xs + (size_t)(s0 + m) * 240 + t * 6;
        acc = bj;
        acc = fmaf(wi0, xm[0], acc); acc = fmaf(wi1, xm[1], acc);
        acc = fmaf(wi2, xm[2], acc); acc = fmaf(wi3, xm[3], acc);
        acc = fmaf(wi4, xm[4], acc); acc = fmaf(wi5, xm[5], acc);
      } else {
        acc = 0.0f;
      }
      const float4* hp = (const float4*)(h_s + m * 128 + kh * 64);
#pragma unroll
      for (int q = 0; q < 16; q++) {
        float4 h4 = hp[q];
        acc = fmaf(w4[q].x, h4.x, acc);
        acc = fmaf(w4[q].y, h4.y, acc);
        acc = fmaf(w4[q].z, h4.z, acc);
        acc = fmaf(w4[q].w, h4.w, acc);
      }
      P[(kh * 12 + m) * 512 + j] = acc;
    }
    __syncthreads();
    // ---- phase 2: activations, c/h update ----
    {
      const int m = p0m, n = pn;
      const float* Pa = P + m * 512;
      const float* Pb = P + (12 + m) * 512;
      float gi = Pa[n] + Pb[n];
      float gf = Pa[n + 128] + Pb[n + 128];
      float gg = Pa[n + 256] + Pb[n + 256];
      float go = Pa[n + 384] + Pb[n + 384];
      c0 = sigm(gf) * c0 + sigm(gi) * tanhf(gg);
      float h = sigm(go) * tanhf(c0);
      h_s[m * 128 + n] = h;
      if (t >= 30) H10[((size_t)(s0 + m) * 10 + (t - 30)) * 128 + n] = h;
    }
    if (tid < 512) {
      const int m = 8 + p0m, n = pn;   // p0m in 0..3 here
      const float* Pa = P + m * 512;
      const float* Pb = P + (12 + m) * 512;
      float gi = Pa[n] + Pb[n];
      float gf = Pa[n + 128] + Pb[n + 128];
      float gg = Pa[n + 256] + Pb[n + 256];
      float go = Pa[n + 384] + Pb[n + 384];
      c1 = sigm(gf) * c1 + sigm(gi) * tanhf(gg);
      float h = sigm(go) * tanhf(c1);
      h_s[m * 128 + n] = h;
      if (t >= 30) H10[((size_t)(s0 + m) * 10 + (t - 30)) * 128 + n] = h;
    }
    __syncthreads();
  }
}

// ---------------------------------------------------------------------------
// Kernel 2a: LayerNorm in-place over rows of H10 ([30000][128]).
// ---------------------------------------------------------------------------
__global__ __launch_bounds__(256) void ln_kernel(
    float* __restrict__ H, const float* __restrict__ g,
    const float* __restrict__ b, int nrows)
{
  int row = blockIdx.x * 4 + (threadIdx.x >> 6);
  int lane = threadIdx.x & 63;
  if (row >= nrows) return;
  float* hr = H + (size_t)row * 128;
  float x0 = hr[lane], x1 = hr[lane + 64];
  float s = x0 + x1;
  for (int off = 32; off > 0; off >>= 1) s += __shfl_xor(s, off);
  float mean = s * (1.0f / 128.0f);
  float d0 = x0 - mean, d1 = x1 - mean;
  float v = d0 * d0 + d1 * d1;
  for (int off = 32; off > 0; off >>= 1) v += __shfl_xor(v, off);
  float rstd = 1.0f / sqrtf(v * (1.0f / 128.0f) + 1e-5f);
  hr[lane] = d0 * rstd * g[lane] + b[lane];
  hr[lane + 64] = d1 * rstd * g[lane + 64] + b[lane + 64];
}

// ---------------------------------------------------------------------------
// Kernel 2b: Out[r] = l2norm(In_row[r] @ W^T). 16 rows per block, 256 threads.
// ---------------------------------------------------------------------------
__global__ __launch_bounds__(256) void proj_kernel(
    const float* __restrict__ In, int inOff, int inStride, int nr,
    const float* __restrict__ W, float* __restrict__ Out)
{
  __shared__ float A_s[16 * 128];   // reused as output staging
  const int tid = threadIdx.x;
  const int r0 = blockIdx.x * 16;

  for (int i = tid; i < 16 * 32; i += 256) {
    int row = i >> 5, c = i & 31;
    int gr = r0 + row;
    float4 v = make_float4(0.f, 0.f, 0.f, 0.f);
    if (gr < nr)
      v = *(const float4*)(In + (size_t)inOff + (size_t)gr * inStride + c * 4);
    *(float4*)(A_s + row * 128 + c * 4) = v;
  }
  __syncthreads();

  const int j = tid & 127, rh = tid >> 7;
  const float* wrow = W + j * 128;
  float acc[8] = {0, 0, 0, 0, 0, 0, 0, 0};
  for (int kc = 0; kc < 32; kc++) {
    float4 wv4 = *(const float4*)(wrow + kc * 4);
#pragma unroll
    for (int i = 0; i < 8; i++) {
      float4 a4 = *(const float4*)(A_s + (rh * 8 + i) * 128 + kc * 4);
      acc[i] = fmaf(wv4.x, a4.x, acc[i]);
      acc[i] = fmaf(wv4.y, a4.y, acc[i]);
      acc[i] = fmaf(wv4.z, a4.z, acc[i]);
      acc[i] = fmaf(wv4.w, a4.w, acc[i]);
    }
  }
  __syncthreads();
#pragma unroll
  for (int i = 0; i < 8; i++) A_s[(rh * 8 + i) * 128 + j] = acc[i];
  __syncthreads();

  const int r = tid >> 4, qq = tid & 15;
  float ss = 0.0f;
#pragma unroll
  for (int i = 0; i < 8; i++) {
    float u = A_s[r * 128 + qq + i * 16];
    ss += u * u;
  }
  for (int off = 8; off > 0; off >>= 1) ss += __shfl_xor(ss, off);
  float scale = 1.0f / fmaxf(sqrtf(ss), 1e-12f);
  int gr = r0 + r;
  if (gr < nr) {
#pragma unroll
    for (int i = 0; i < 8; i++)
      Out[(size_t)gr * 128 + qq + i * 16] = A_s[r * 128 + qq + i * 16] * scale;
  }
}

// ---------------------------------------------------------------------------
// Kernel 3: attention scores + per-chunk top-5 — register-tiled 4x8.
// grid (16 chunks, 47 target-blocks) x 256 threads, 1 block/CU (99 KB LDS).
// Thread (r = tid&15, cg = tid>>4): targets {r,r+16,r+32,r+48},
// cols cg*8..cg*8+7 of each 128-col panel. 12 ds_read_b128 -> 128 FMA per kc.
// K panels double-buffered through registers (16 float4 prefetch).
// ---------------------------------------------------------------------------
__global__ __launch_bounds__(256, 1) void score_kernel(
    const float* __restrict__ Qn, const float* __restrict__ Kn,
    const int* __restrict__ tix, const float* __restrict__ log_temp,
    const float* __restrict__ lag_bias, float* __restrict__ part)
{
  __shared__ float Q_lds[64 * 132];    // padded: lane-strided reads, 2-way free
  __shared__ float K_lds[128 * 128];   // unpadded: reads are broadcast
  const int tid = threadIdx.x;
  const int chunk = blockIdx.x;
  const int T0 = blockIdx.y * 64;
  const int r = tid & 15;
  const int cg = tid >> 4;             // 0..15
  const int colBase0 = chunk * CHUNK_COLS;
  const int colEnd = colBase0 + CHUNK_COLS;

  // ---- stage gathered Q rows ----
  for (int i = tid; i < 64 * 32; i += 256) {
    int row = i >> 5, c = i & 31;
    int tgt = T0 + row;
    float4 v = make_float4(0.f, 0.f, 0.f, 0.f);
    if (tgt < S_N) {
      int src = tix[tgt];
      v = *(const float4*)(Qn + (size_t)src * 128 + c * 4);
    }
    *(float4*)(Q_lds + row * 132 + c * 4) = v;
  }

  // ---- stage K panel 0 (full 128 cols always: CHUNK_COLS > PANEL) ----
#pragma unroll
  for (int j = 0; j < 16; j++) {
    int i = tid + j * 256;
    int row = i >> 5, c = i & 31;
    *(float4*)(K_lds + row * 128 + c * 4) =
        *(const float4*)(Kn + (size_t)(colBase0 + row) * 128 + c * 4);
  }

  float invtemp;
  float lb[10];
  int myTix[4];
  {
    float temp = fminf(fmaxf(expf(log_temp[0]), 0.1f), 11.313708499f);
    invtemp = 1.0f / temp;
#pragma unroll
    for (int l = 0; l < 10; l++) lb[l] = lag_bias[l];
#pragma unroll
    for (int t = 0; t < 4; t++) {
      int tgt = T0 + r + t * 16;
      myTix[t] = (tgt < S_N) ? tix[tgt] : -1;
    }
  }

  float tv[4][5];
  int txi[4][5];
#pragma unroll
  for (int t = 0; t < 4; t++)
#pragma unroll
    for (int q = 0; q < 5; q++) { tv[t][q] = -3e38f; txi[t][q] = 0x7fffffff; }

  __syncthreads();

  const int npanels = (CHUNK_COLS + PANEL - 1) / PANEL;   // 15
  for (int p = 0; p < npanels; p++) {
    // prefetch next panel into registers (in flight during compute)
    float4 kreg[16];
    const int nb = colBase0 + (p + 1) * PANEL;
    if (p + 1 < npanels) {
#pragma unroll
      for (int j = 0; j < 16; j++) {
        int i = tid + j * 256;
        int row = i >> 5, c = i & 31;
        int col = nb + row;
        kreg[j] = (col < colEnd)
                      ? *(const float4*)(Kn + (size_t)col * 128 + c * 4)
                      : make_float4(0.f, 0.f, 0.f, 0.f);
      }
    }

    // ---- compute panel p ----
    float a[4][8];
#pragma unroll
    for (int t = 0; t < 4; t++)
#pragma unroll
      for (int c = 0; c < 8; c++) a[t][c] = 0.0f;

    const float* qbase = Q_lds + r * 132;
    const float* kbase = K_lds + (cg * 8) * 128;
#pragma unroll 2
    for (int kc = 0; kc < 32; kc++) {
      float4 q4[4], b4[8];
#pragma unroll
      for (int t = 0; t < 4; t++)
        q4[t] = *(const float4*)(qbase + t * 16 * 132 + kc * 4);
#pragma unroll
      for (int c = 0; c < 8; c++)
        b4[c] = *(const float4*)(kbase + c * 128 + kc * 4);
#pragma unroll
      for (int t = 0; t < 4; t++)
#pragma unroll
        for (int c = 0; c < 8; c++) {
          a[t][c] = fmaf(q4[t].x, b4[c].x, a[t][c]);
          a[t][c] = fmaf(q4[t].y, b4[c].y, a[t][c]);
          a[t][c] = fmaf(q4[t].z, b4[c].z, a[t][c]);
          a[t][c] = fmaf(q4[t].w, b4[c].w, a[t][c]);
        }
    }

    // ---- score + streaming top-5 insert (cols ascending per thread) ----
    const int pcb = colBase0 + p * PANEL + cg * 8;
#pragma unroll
    for (int c = 0; c < 8; c++) {
      int col = pcb + c;
      int scol = col / 10;
      int lcol = col - scol * 10;
      if (col < colEnd) {
#pragma unroll
        for (int t = 0; t < 4; t++) {
          if (scol != myTix[t]) {
            float vsc = a[t][c] * invtemp + lb[lcol];
            ins_stream(tv[t], txi[t], vsc, col);
          }
        }
      }
    }

    __syncthreads();   // all readers of K_lds done
    if (p + 1 < npanels) {
#pragma unroll
      for (int j = 0; j < 16; j++) {
        int i = tid + j * 256;
        *(float4*)(K_lds + (i >> 5) * 128 + (i & 31) * 4) = kreg[j];
      }
    }
    __syncthreads();   // K_lds ready (or merge-buffer safe on last iter)
  }

  // ---- merge 16 colgroup partials per target ----
  float* M = K_lds;   // [64 targets][16 cg][10]
#pragma unroll
  for (int t = 0; t < 4; t++) {
    float* my = M + ((r + t * 16) * 16 + cg) * 10;
#pragma unroll
    for (int q = 0; q < 5; q++) {
      my[q * 2] = tv[t][q];
      my[q * 2 + 1] = __int_as_float(txi[t][q]);
    }
  }
  __syncthreads();
  if (tid < 64 && T0 + tid < S_N) {
    float v[5];
    int ix[5];
#pragma unroll
    for (int q = 0; q < 5; q++) { v[q] = -3e38f; ix[q] = 0x7fffffff; }
    for (int g = 0; g < 16; g++) {
      const float* src = M + (tid * 16 + g) * 10;
#pragma unroll
      for (int q = 0; q < 5; q++)
        ins_full(v, ix, src[q * 2], __float_as_int(src[q * 2 + 1]));
    }
    float* dst = part + ((size_t)(T0 + tid) * NCHUNK + chunk) * 10;
#pragma unroll
    for (int q = 0; q < 5; q++) {
      dst[q * 2] = v[q];
      dst[q * 2 + 1] = __int_as_float(ix[q]);
    }
  }
}

// ---------------------------------------------------------------------------
// Kernel 4: merge 16 chunk top-5s -> global top-5, softmax, gather z, MLP.
// ---------------------------------------------------------------------------
__global__ __launch_bounds__(256) void final_kernel(
    const float* __restrict__ part, const float* __restrict__ Xraw,
    const float* __restrict__ W1, const float* __restrict__ b1,
    const float* __restrict__ W2, const float* __restrict__ b2,
    const float* __restrict__ W3, const float* __restrict__ b3,
    float* __restrict__ out)
{
  __shared__ float W1s[64 * 12];
  __shared__ float W2s[32 * 64];
  __shared__ float b1s[64];
  __shared__ float b2s[32];
  __shared__ float W3s[32];
  const int tid = threadIdx.x;
  for (int i = tid; i < 768; i += 256) W1s[i] = W1[i];
  for (int i = tid; i < 2048; i += 256) W2s[i] = W2[i];
  if (tid < 64) b1s[tid] = b1[tid];
  if (tid < 32) { b2s[tid] = b2[tid]; W3s[tid] = W3[tid]; }
  __syncthreads();

  int t = blockIdx.x * 256 + tid;
  if (t >= S_N) return;

  float v[5];
  int ix[5];
#pragma unroll
  for (int q = 0; q < 5; q++) { v[q] = -3e38f; ix[q] = 0x7fffffff; }
  const float* pp = part + (size_t)t * (NCHUNK * 10);
  for (int c = 0; c < NCHUNK * 5; c++)
    ins_full(v, ix, pp[c * 2], __float_as_int(pp[c * 2 + 1]));

  // softmax over v; v[0] is max by construction
  float e1 = expf(v[1] - v[0]), e2 = expf(v[2] - v[0]),
        e3 = expf(v[3] - v[0]), e4 = expf(v[4] - v[0]);
  float rs = 1.0f / (1.0f + e1 + e2 + e3 + e4);
  float w_[5] = {rs, e1 * rs, e2 * rs, e3 * rs, e4 * rs};

  float feat[12];
#pragma unroll
  for (int f = 0; f < 12; f++) feat[f] = 0.0f;
#pragma unroll
  for (int q = 0; q < 5; q++) {
    int iq = ix[q];
    int s = iq / 10;
    int l = iq - 10 * s;
    int pos = 29 + l;   // clip(L-1-(L_MAX-l), 0, L-1)
    const float* zp = Xraw + (size_t)s * 240 + pos * 6;
#pragma unroll
    for (int f = 0; f < 6; f++) {
      float z = zp[f];
      feat[f] += w_[q] * z;
      if (q == 0) feat[6 + f] = z;
    }
  }

  float h1[64];
#pragma unroll 4
  for (int o = 0; o < 64; o++) {
    float acc = b1s[o];
    const float* wr = W1s + o * 12;
#pragma unroll
    for (int f = 0; f < 12; f++) acc = fmaf(wr[f], feat[f], acc);
    h1[o] = fmaxf(acc, 0.0f);
  }
  float rr = b3[0];
#pragma unroll 2
  for (int o = 0; o < 32; o++) {
    float acc = b2s[o];
    const float* wr = W2s + o * 64;
#pragma unroll 8
    for (int k = 0; k < 64; k++) acc = fmaf(wr[k], h1[k], acc);
    rr = fmaf(W3s[o], fmaxf(acc, 0.0f), rr);
  }
  out[t] = rr;
}

// ---------------------------------------------------------------------------
extern "C" void kernel_launch(void* const* d_in, const int* in_sizes, int n_in,
                              void* d_out, int out_size, void* d_ws,
                              size_t ws_size, hipStream_t stream) {
  const float* Xs   = (const float*)d_in[0];
  const float* Xraw = (const float*)d_in[1];
  const int*   tix  = (const int*)d_in[2];
  const float* Wih  = (const float*)d_in[3];
  const float* Whh  = (const float*)d_in[4];
  const float* bih  = (const float*)d_in[5];
  const float* bhh  = (const float*)d_in[6];
  const float* ln_g = (const float*)d_in[7];
  const float* ln_b = (const float*)d_in[8];
  const float* WQ   = (const float*)d_in[9];
  const float* WK   = (const float*)d_in[10];
  const float* log_temp = (const float*)d_in[11];
  const float* lag_bias = (const float*)d_in[12];
  const float* W1 = (const float*)d_in[13];
  const float* b1 = (const float*)d_in[14];
  const float* W2 = (const float*)d_in[15];
  const float* b2 = (const float*)d_in[16];
  const float* W3 = (const float*)d_in[17];
  const float* b3 = (const float*)d_in[18];
  float* outp = (float*)d_out;

  float* ws = (float*)d_ws;
  float* H10 = ws;                    // 3000*10*128 = 3,840,000
  float* Kn  = ws + 3840000;          // 30000*128   = 3,840,000
  float* Qn  = ws + 7680000;          // 3000*128    =   384,000
  float* part = ws + 8064000;         // 3000*16*10  =   480,000

  lstm_kernel<<<250, 1024, 0, stream>>>(Xs, Wih, Whh, bih, bhh, H10);
  ln_kernel<<<7500, 256, 0, stream>>>(H10, ln_g, ln_b, 30000);
  proj_kernel<<<1875, 256, 0, stream>>>(H10, 0, 128, 30000, WK, Kn);
  proj_kernel<<<188, 256, 0, stream>>>(H10, 9 * 128, 1280, 3000, WQ, Qn);
  {
    dim3 grid(NCHUNK, 47);
    score_kernel<<<grid, 256, 0, stream>>>(Qn, Kn, tix, log_temp, lag_bias,
                                           part);
  }
  final_kernel<<<12, 256, 0, stream>>>(part, Xraw, W1, b1, W2, b2, W3, b3,
                                       outp);
}

// Round 3
// 1052.129 us; speedup vs baseline: 1.2474x; 1.2474x over previous
//
#include <hip/hip_runtime.h>
#include <math.h>

#define S_N 3000
#define NCOLS 30000
#define NCHUNK 21
#define CHUNK_COLS 1429   // ceil(30000/21)
#define PANEL 64

__device__ __forceinline__ float sigm(float x) { return 1.0f / (1.0f + expf(-x)); }

__device__ __forceinline__ void ins_stream(float (&v)[5], int (&ix)[5],
                                           float nv, int ni) {
  // candidates arrive in ascending index order -> strict > == lax.top_k tie rule
  if (nv > v[4]) {
    if (nv > v[3]) { v[4] = v[3]; ix[4] = ix[3];
      if (nv > v[2]) { v[3] = v[2]; ix[3] = ix[2];
        if (nv > v[1]) { v[2] = v[1]; ix[2] = ix[1];
          if (nv > v[0]) { v[1] = v[0]; ix[1] = ix[0]; v[0] = nv; ix[0] = ni; }
          else { v[1] = nv; ix[1] = ni; }
        } else { v[2] = nv; ix[2] = ni; }
      } else { v[3] = nv; ix[3] = ni; }
    } else { v[4] = nv; ix[4] = ni; }
  }
}

__device__ __forceinline__ bool bet(float av, int ai, float bv, int bi) {
  return (av > bv) || (av == bv && ai < bi);
}

__device__ __forceinline__ void ins_full(float (&v)[5], int (&ix)[5],
                                         float nv, int ni) {
  if (bet(nv, ni, v[4], ix[4])) {
    if (bet(nv, ni, v[3], ix[3])) { v[4] = v[3]; ix[4] = ix[3];
      if (bet(nv, ni, v[2], ix[2])) { v[3] = v[2]; ix[3] = ix[2];
        if (bet(nv, ni, v[1], ix[1])) { v[2] = v[1]; ix[2] = ix[1];
          if (bet(nv, ni, v[0], ix[0])) { v[1] = v[0]; ix[1] = ix[0]; v[0] = nv; ix[0] = ni; }
          else { v[1] = nv; ix[1] = ni; }
        } else { v[2] = nv; ix[2] = ni; }
      } else { v[3] = nv; ix[3] = ni; }
    } else { v[4] = nv; ix[4] = ni; }
  }
}

// ---------------------------------------------------------------------------
// Kernel 1: LSTM. 250 blocks x 1024 threads; each block owns 12 sequences.
// Each lane holds Whh[j][kh*64 .. kh*64+63] stationary in 64 VGPRs.
// ---------------------------------------------------------------------------
__global__ __launch_bounds__(1024, 4) void lstm_kernel(
    const float* __restrict__ Xs, const float* __restrict__ Wih,
    const float* __restrict__ Whh, const float* __restrict__ bih,
    const float* __restrict__ bhh, float* __restrict__ H10)
{
  __shared__ float h_s[12 * 128];       // 6 KB
  __shared__ float P[2 * 12 * 512];     // 48 KB
  const int tid = threadIdx.x;
  const int s0 = blockIdx.x * 12;

  for (int i = tid; i < 12 * 128; i += 1024) h_s[i] = 0.0f;

  const int lane = tid & 63;
  const int wv = tid >> 6;
  const int j = (wv & 7) * 64 + lane;
  const int kh = wv >> 3;

  float4 w4[16];
  {
    const float4* wr = (const float4*)(Whh + j * 128 + kh * 64);
#pragma unroll
    for (int q = 0; q < 16; q++) w4[q] = wr[q];
  }
  float wi0 = 0, wi1 = 0, wi2 = 0, wi3 = 0, wi4 = 0, wi5 = 0, bj = 0;
  if (kh == 0) {
    wi0 = Wih[j * 6 + 0]; wi1 = Wih[j * 6 + 1]; wi2 = Wih[j * 6 + 2];
    wi3 = Wih[j * 6 + 3]; wi4 = Wih[j * 6 + 4]; wi5 = Wih[j * 6 + 5];
    bj = bih[j] + bhh[j];
  }

  float c0 = 0.0f, c1 = 0.0f;
  const int p0m = tid >> 7;      // 0..7
  const int pn = tid & 127;

  __syncthreads();

  for (int t = 0; t < 40; t++) {
    // ---- phase 1: gate pre-activations ----
#pragma unroll 1
    for (int m = 0; m < 12; m++) {
      float acc;
      if (kh == 0) {
        const float* xm = Xs + (size_t)(s0 + m) * 240 + t * 6;
        acc = bj;
        acc = fmaf(wi0, xm[0], acc); acc = fmaf(wi1, xm[1], acc);
        acc = fmaf(wi2, xm[2], acc); acc = fmaf(wi3, xm[3], acc);
        acc = fmaf(wi4, xm[4], acc); acc = fmaf(wi5, xm[5], acc);
      } else {
        acc = 0.0f;
      }
      const float4* hp = (const float4*)(h_s + m * 128 + kh * 64);
#pragma unroll
      for (int q = 0; q < 16; q++) {
        float4 h4 = hp[q];
        acc = fmaf(w4[q].x, h4.x, acc);
        acc = fmaf(w4[q].y, h4.y, acc);
        acc = fmaf(w4[q].z, h4.z, acc);
        acc = fmaf(w4[q].w, h4.w, acc);
      }
      P[(kh * 12 + m) * 512 + j] = acc;
    }
    __syncthreads();
    // ---- phase 2: activations, c/h update ----
    {
      const int m = p0m, n = pn;
      const float* Pa = P + m * 512;
      const float* Pb = P + (12 + m) * 512;
      float gi = Pa[n] + Pb[n];
      float gf = Pa[n + 128] + Pb[n + 128];
      float gg = Pa[n + 256] + Pb[n + 256];
      float go = Pa[n + 384] + Pb[n + 384];
      c0 = sigm(gf) * c0 + sigm(gi) * tanhf(gg);
      float h = sigm(go) * tanhf(c0);
      h_s[m * 128 + n] = h;
      if (t >= 30) H10[((size_t)(s0 + m) * 10 + (t - 30)) * 128 + n] = h;
    }
    if (tid < 512) {
      const int m = 8 + p0m, n = pn;   // p0m in 0..3 here
      const float* Pa = P + m * 512;
      const float* Pb = P + (12 + m) * 512;
      float gi = Pa[n] + Pb[n];
      float gf = Pa[n + 128] + Pb[n + 128];
      float gg = Pa[n + 256] + Pb[n + 256];
      float go = Pa[n + 384] + Pb[n + 384];
      c1 = sigm(gf) * c1 + sigm(gi) * tanhf(gg);
      float h = sigm(go) * tanhf(c1);
      h_s[m * 128 + n] = h;
      if (t >= 30) H10[((size_t)(s0 + m) * 10 + (t - 30)) * 128 + n] = h;
    }
    __syncthreads();
  }
}

// ---------------------------------------------------------------------------
// Kernel 2a: LayerNorm in-place over rows of H10 ([30000][128]).
// ---------------------------------------------------------------------------
__global__ __launch_bounds__(256) void ln_kernel(
    float* __restrict__ H, const float* __restrict__ g,
    const float* __restrict__ b, int nrows)
{
  int row = blockIdx.x * 4 + (threadIdx.x >> 6);
  int lane = threadIdx.x & 63;
  if (row >= nrows) return;
  float* hr = H + (size_t)row * 128;
  float x0 = hr[lane], x1 = hr[lane + 64];
  float s = x0 + x1;
  for (int off = 32; off > 0; off >>= 1) s += __shfl_xor(s, off);
  float mean = s * (1.0f / 128.0f);
  float d0 = x0 - mean, d1 = x1 - mean;
  float v = d0 * d0 + d1 * d1;
  for (int off = 32; off > 0; off >>= 1) v += __shfl_xor(v, off);
  float rstd = 1.0f / sqrtf(v * (1.0f / 128.0f) + 1e-5f);
  hr[lane] = d0 * rstd * g[lane] + b[lane];
  hr[lane + 64] = d1 * rstd * g[lane + 64] + b[lane + 64];
}

// ---------------------------------------------------------------------------
// Kernel 2b: Out[r] = l2norm(In_row[r] @ W^T). 16 rows per block, 256 threads.
// ---------------------------------------------------------------------------
__global__ __launch_bounds__(256) void proj_kernel(
    const float* __restrict__ In, int inOff, int inStride, int nr,
    const float* __restrict__ W, float* __restrict__ Out)
{
  __shared__ float A_s[16 * 128];   // reused as output staging
  const int tid = threadIdx.x;
  const int r0 = blockIdx.x * 16;

  for (int i = tid; i < 16 * 32; i += 256) {
    int row = i >> 5, c = i & 31;
    int gr = r0 + row;
    float4 v = make_float4(0.f, 0.f, 0.f, 0.f);
    if (gr < nr)
      v = *(const float4*)(In + (size_t)inOff + (size_t)gr * inStride + c * 4);
    *(float4*)(A_s + row * 128 + c * 4) = v;
  }
  __syncthreads();

  const int j = tid & 127, rh = tid >> 7;
  const float* wrow = W + j * 128;
  float acc[8] = {0, 0, 0, 0, 0, 0, 0, 0};
  for (int kc = 0; kc < 32; kc++) {
    float4 wv4 = *(const float4*)(wrow + kc * 4);
#pragma unroll
    for (int i = 0; i < 8; i++) {
      float4 a4 = *(const float4*)(A_s + (rh * 8 + i) * 128 + kc * 4);
      acc[i] = fmaf(wv4.x, a4.x, acc[i]);
      acc[i] = fmaf(wv4.y, a4.y, acc[i]);
      acc[i] = fmaf(wv4.z, a4.z, acc[i]);
      acc[i] = fmaf(wv4.w, a4.w, acc[i]);
    }
  }
  __syncthreads();
#pragma unroll
  for (int i = 0; i < 8; i++) A_s[(rh * 8 + i) * 128 + j] = acc[i];
  __syncthreads();

  const int r = tid >> 4, qq = tid & 15;
  float ss = 0.0f;
#pragma unroll
  for (int i = 0; i < 8; i++) {
    float u = A_s[r * 128 + qq + i * 16];
    ss += u * u;
  }
  for (int off = 8; off > 0; off >>= 1) ss += __shfl_xor(ss, off);
  float scale = 1.0f / fmaxf(sqrtf(ss), 1e-12f);
  int gr = r0 + r;
  if (gr < nr) {
#pragma unroll
    for (int i = 0; i < 8; i++)
      Out[(size_t)gr * 128 + qq + i * 16] = A_s[r * 128 + qq + i * 16] * scale;
  }
}

// ---------------------------------------------------------------------------
// Kernel 3: attention scores + per-chunk top-5 — register-tiled 4x4,
// conflict-free LDS (both arrays stride-132), PANEL=64, 2 blocks/CU.
// Thread (r = tid&15, cg = tid>>4): targets {r,r+16,r+32,r+48},
// cols {cg*4 .. cg*4+3} of each 64-col panel.
// Q read: 16 addrs/wave, 2-way bank alias (free), 4-lane broadcast.
// K read: 4 addrs/wave spaced 2112B -> 2-way bank alias (free), 16-lane bcast.
// ---------------------------------------------------------------------------
__global__ __launch_bounds__(256, 2) void score_kernel(
    const float* __restrict__ Qn, const float* __restrict__ Kn,
    const int* __restrict__ tix, const float* __restrict__ log_temp,
    const float* __restrict__ lag_bias, float* __restrict__ part)
{
  __shared__ float Q_lds[64 * 132];    // 33.8 KB
  __shared__ float K_lds[64 * 132];    // 33.8 KB (reused as merge buffer)
  const int tid = threadIdx.x;
  const int chunk = blockIdx.x;
  const int T0 = blockIdx.y * 64;
  const int r = tid & 15;
  const int cg = tid >> 4;             // 0..15
  const int colBase0 = chunk * CHUNK_COLS;
  const int colEnd = (colBase0 + CHUNK_COLS < NCOLS) ? colBase0 + CHUNK_COLS
                                                     : NCOLS;

  // ---- stage gathered Q rows ----
  for (int i = tid; i < 64 * 32; i += 256) {
    int row = i >> 5, c = i & 31;
    int tgt = T0 + row;
    float4 v = make_float4(0.f, 0.f, 0.f, 0.f);
    if (tgt < S_N) {
      int src = tix[tgt];
      v = *(const float4*)(Qn + (size_t)src * 128 + c * 4);
    }
    *(float4*)(Q_lds + row * 132 + c * 4) = v;
  }

  float invtemp;
  float lb[10];
  int myTix[4];
  {
    float temp = fminf(fmaxf(expf(log_temp[0]), 0.1f), 11.313708499f);
    invtemp = 1.0f / temp;
#pragma unroll
    for (int l = 0; l < 10; l++) lb[l] = lag_bias[l];
#pragma unroll
    for (int t = 0; t < 4; t++) {
      int tgt = T0 + r + t * 16;
      myTix[t] = (tgt < S_N) ? tix[tgt] : -1;
    }
  }

  float tv[4][5];
  int txi[4][5];
#pragma unroll
  for (int t = 0; t < 4; t++)
#pragma unroll
    for (int q = 0; q < 5; q++) { tv[t][q] = -3e38f; txi[t][q] = 0x7fffffff; }

  const int npanels = (colEnd - colBase0 + PANEL - 1) / PANEL;
  for (int p = 0; p < npanels; p++) {
    const int pcb = colBase0 + p * PANEL;
    __syncthreads();   // previous panel's readers done (covers Q stage on p=0)
    // stage K panel: 64 cols x 32 float4; global reads fully coalesced
#pragma unroll
    for (int j = 0; j < 8; j++) {
      int i = tid + j * 256;
      int col = i >> 5, kk = i & 31;
      int gcol = pcb + col;
      int src = (gcol < NCOLS) ? gcol : 0;
      float4 v = *(const float4*)(Kn + (size_t)src * 128 + kk * 4);
      *(float4*)(K_lds + col * 132 + kk * 4) = v;
    }
    __syncthreads();

    // ---- compute: 4 targets x 4 cols, K = 128 ----
    float a[4][4];
#pragma unroll
    for (int t = 0; t < 4; t++)
#pragma unroll
      for (int c = 0; c < 4; c++) a[t][c] = 0.0f;

    const float* qb = Q_lds + r * 132;
    const float* kb = K_lds + (cg * 4) * 132;
#pragma unroll 4
    for (int kc = 0; kc < 32; kc++) {
      float4 q4[4], b4[4];
#pragma unroll
      for (int t = 0; t < 4; t++)
        q4[t] = *(const float4*)(qb + t * 16 * 132 + kc * 4);
#pragma unroll
      for (int c = 0; c < 4; c++)
        b4[c] = *(const float4*)(kb + c * 132 + kc * 4);
#pragma unroll
      for (int t = 0; t < 4; t++)
#pragma unroll
        for (int c = 0; c < 4; c++) {
          a[t][c] = fmaf(q4[t].x, b4[c].x, a[t][c]);
          a[t][c] = fmaf(q4[t].y, b4[c].y, a[t][c]);
          a[t][c] = fmaf(q4[t].z, b4[c].z, a[t][c]);
          a[t][c] = fmaf(q4[t].w, b4[c].w, a[t][c]);
        }
    }

    // ---- score + streaming top-5 insert (cols ascending per thread) ----
#pragma unroll
    for (int c = 0; c < 4; c++) {
      int col = pcb + cg * 4 + c;
      if (col < colEnd) {
        int scol = col / 10;
        int lcol = col - scol * 10;
#pragma unroll
        for (int t = 0; t < 4; t++) {
          if (scol != myTix[t]) {
            float vsc = a[t][c] * invtemp + lb[lcol];
            ins_stream(tv[t], txi[t], vsc, col);
          }
        }
      }
    }
  }

  // ---- merge 16 colgroup partials per target ----
  __syncthreads();
  float* M = K_lds;   // [64 targets][16 cg][10]
#pragma unroll
  for (int t = 0; t < 4; t++) {
    float* my = M + ((r + t * 16) * 16 + cg) * 10;
#pragma unroll
    for (int q = 0; q < 5; q++) {
      my[q * 2] = tv[t][q];
      my[q * 2 + 1] = __int_as_float(txi[t][q]);
    }
  }
  __syncthreads();
  if (tid < 64 && T0 + tid < S_N) {
    float v[5];
    int ix[5];
#pragma unroll
    for (int q = 0; q < 5; q++) { v[q] = -3e38f; ix[q] = 0x7fffffff; }
    for (int g = 0; g < 16; g++) {
      const float* src = M + (tid * 16 + g) * 10;
#pragma unroll
      for (int q = 0; q < 5; q++)
        ins_full(v, ix, src[q * 2], __float_as_int(src[q * 2 + 1]));
    }
    float* dst = part + ((size_t)(T0 + tid) * NCHUNK + chunk) * 10;
#pragma unroll
    for (int q = 0; q < 5; q++) {
      dst[q * 2] = v[q];
      dst[q * 2 + 1] = __int_as_float(ix[q]);
    }
  }
}

// ---------------------------------------------------------------------------
// Kernel 4: merge NCHUNK chunk top-5s -> global top-5, softmax, gather z, MLP.
// ---------------------------------------------------------------------------
__global__ __launch_bounds__(256) void final_kernel(
    const float* __restrict__ part, const float* __restrict__ Xraw,
    const float* __restrict__ W1, const float* __restrict__ b1,
    const float* __restrict__ W2, const float* __restrict__ b2,
    const float* __restrict__ W3, const float* __restrict__ b3,
    float* __restrict__ out)
{
  __shared__ float W1s[64 * 12];
  __shared__ float W2s[32 * 64];
  __shared__ float b1s[64];
  __shared__ float b2s[32];
  __shared__ float W3s[32];
  const int tid = threadIdx.x;
  for (int i = tid; i < 768; i += 256) W1s[i] = W1[i];
  for (int i = tid; i < 2048; i += 256) W2s[i] = W2[i];
  if (tid < 64) b1s[tid] = b1[tid];
  if (tid < 32) { b2s[tid] = b2[tid]; W3s[tid] = W3[tid]; }
  __syncthreads();

  int t = blockIdx.x * 256 + tid;
  if (t >= S_N) return;

  float v[5];
  int ix[5];
#pragma unroll
  for (int q = 0; q < 5; q++) { v[q] = -3e38f; ix[q] = 0x7fffffff; }
  const float* pp = part + (size_t)t * (NCHUNK * 10);
  for (int c = 0; c < NCHUNK * 5; c++)
    ins_full(v, ix, pp[c * 2], __float_as_int(pp[c * 2 + 1]));

  // softmax over v; v[0] is max by construction
  float e1 = expf(v[1] - v[0]), e2 = expf(v[2] - v[0]),
        e3 = expf(v[3] - v[0]), e4 = expf(v[4] - v[0]);
  float rs = 1.0f / (1.0f + e1 + e2 + e3 + e4);
  float w_[5] = {rs, e1 * rs, e2 * rs, e3 * rs, e4 * rs};

  float feat[12];
#pragma unroll
  for (int f = 0; f < 12; f++) feat[f] = 0.0f;
#pragma unroll
  for (int q = 0; q < 5; q++) {
    int iq = ix[q];
    int s = iq / 10;
    int l = iq - 10 * s;
    int pos = 29 + l;   // clip(L-1-(L_MAX-l), 0, L-1)
    const float* zp = Xraw + (size_t)s * 240 + pos * 6;
#pragma unroll
    for (int f = 0; f < 6; f++) {
      float z = zp[f];
      feat[f] += w_[q] * z;
      if (q == 0) feat[6 + f] = z;
    }
  }

  float h1[64];
#pragma unroll 4
  for (int o = 0; o < 64; o++) {
    float acc = b1s[o];
    const float* wr = W1s + o * 12;
#pragma unroll
    for (int f = 0; f < 12; f++) acc = fmaf(wr[f], feat[f], acc);
    h1[o] = fmaxf(acc, 0.0f);
  }
  float rr = b3[0];
#pragma unroll 2
  for (int o = 0; o < 32; o++) {
    float acc = b2s[o];
    const float* wr = W2s + o * 64;
#pragma unroll 8
    for (int k = 0; k < 64; k++) acc = fmaf(wr[k], h1[k], acc);
    rr = fmaf(W3s[o], fmaxf(acc, 0.0f), rr);
  }
  out[t] = rr;
}

// ---------------------------------------------------------------------------
extern "C" void kernel_launch(void* const* d_in, const int* in_sizes, int n_in,
                              void* d_out, int out_size, void* d_ws,
                              size_t ws_size, hipStream_t stream) {
  const float* Xs   = (const float*)d_in[0];
  const float* Xraw = (const float*)d_in[1];
  const int*   tix  = (const int*)d_in[2];
  const float* Wih  = (const float*)d_in[3];
  const float* Whh  = (const float*)d_in[4];
  const float* bih  = (const float*)d_in[5];
  const float* bhh  = (const float*)d_in[6];
  const float* ln_g = (const float*)d_in[7];
  const float* ln_b = (const float*)d_in[8];
  const float* WQ   = (const float*)d_in[9];
  const float* WK   = (const float*)d_in[10];
  const float* log_temp = (const float*)d_in[11];
  const float* lag_bias = (const float*)d_in[12];
  const float* W1 = (const float*)d_in[13];
  const float* b1 = (const float*)d_in[14];
  const float* W2 = (const float*)d_in[15];
  const float* b2 = (const float*)d_in[16];
  const float* W3 = (const float*)d_in[17];
  const float* b3 = (const float*)d_in[18];
  float* outp = (float*)d_out;

  float* ws = (float*)d_ws;
  float* H10 = ws;                    // 3000*10*128 = 3,840,000 floats
  float* Kn  = ws + 3840000;          // 30000*128   = 3,840,000
  float* Qn  = ws + 7680000;          // 3000*128    =   384,000
  // part aliases H10: H10 is dead once the proj kernels have produced Kn/Qn,
  // and score_kernel (which writes part) runs strictly after them.
  float* part = H10;                  // 3000*21*10  =   630,000 <= 3,840,000

  lstm_kernel<<<250, 1024, 0, stream>>>(Xs, Wih, Whh, bih, bhh, H10);
  ln_kernel<<<7500, 256, 0, stream>>>(H10, ln_g, ln_b, 30000);
  proj_kernel<<<1875, 256, 0, stream>>>(H10, 0, 128, 30000, WK, Kn);
  proj_kernel<<<188, 256, 0, stream>>>(H10, 9 * 128, 1280, 3000, WQ, Qn);
  {
    dim3 grid(NCHUNK, 47);
    score_kernel<<<grid, 256, 0, stream>>>(Qn, Kn, tix, log_temp, lag_bias,
                                           part);
  }
  final_kernel<<<12, 256, 0, stream>>>(part, Xraw, W1, b1, W2, b2, W3, b3,
                                       outp);
}

// Round 4
// 948.056 us; speedup vs baseline: 1.3843x; 1.1098x over previous
//
#include <hip/hip_runtime.h>
#include <math.h>

#define S_N 3000
#define NCOLS 30000
#define SCHUNK 16
#define SC_COLS 1875    // 30000/16

typedef __bf16 v8bf __attribute__((ext_vector_type(8)));
typedef float v16f __attribute__((ext_vector_type(16)));

__device__ __forceinline__ float sigm(float x) { return 1.0f / (1.0f + expf(-x)); }

__device__ __forceinline__ bool bet(float av, int ai, float bv, int bi) {
  return (av > bv) || (av == bv && ai < bi);
}

// streaming insert (candidates ascending by index): strict > == lax.top_k tie rule
template <int M>
__device__ __forceinline__ void insS(float (&v)[M], int (&ix)[M], float nv, int ni) {
  if (!(nv > v[M - 1])) return;
  bool b[M];
#pragma unroll
  for (int q = 0; q < M; q++) b[q] = nv > v[q];
#pragma unroll
  for (int q = M - 1; q > 0; q--) {
    v[q]  = b[q] ? (b[q - 1] ? v[q - 1] : nv) : v[q];
    ix[q] = b[q] ? (b[q - 1] ? ix[q - 1] : ni) : ix[q];
  }
  if (b[0]) { v[0] = nv; ix[0] = ni; }
}

// full comparator insert (value desc, index asc) for arbitrary-order merges
template <int M>
__device__ __forceinline__ void insF(float (&v)[M], int (&ix)[M], float nv, int ni) {
  if (!bet(nv, ni, v[M - 1], ix[M - 1])) return;
  bool b[M];
#pragma unroll
  for (int q = 0; q < M; q++) b[q] = bet(nv, ni, v[q], ix[q]);
#pragma unroll
  for (int q = M - 1; q > 0; q--) {
    v[q]  = b[q] ? (b[q - 1] ? v[q - 1] : nv) : v[q];
    ix[q] = b[q] ? (b[q - 1] ? ix[q - 1] : ni) : ix[q];
  }
  if (b[0]) { v[0] = nv; ix[0] = ni; }
}

__device__ __forceinline__ unsigned short f2bf_rne(float f) {
  unsigned int u = __float_as_uint(f);
  unsigned int r = (u + 0x7fffu + ((u >> 16) & 1u)) >> 16;
  return (unsigned short)r;
}
__device__ __forceinline__ float bf2f(unsigned short h) {
  return __uint_as_float(((unsigned int)h) << 16);
}

// ---------------------------------------------------------------------------
// Kernel 1: LSTM (unchanged from R3). 250 blocks x 1024 threads.
// ---------------------------------------------------------------------------
__global__ __launch_bounds__(1024, 4) void lstm_kernel(
    const float* __restrict__ Xs, const float* __restrict__ Wih,
    const float* __restrict__ Whh, const float* __restrict__ bih,
    const float* __restrict__ bhh, float* __restrict__ H10)
{
  __shared__ float h_s[12 * 128];
  __shared__ float P[2 * 12 * 512];
  const int tid = threadIdx.x;
  const int s0 = blockIdx.x * 12;

  for (int i = tid; i < 12 * 128; i += 1024) h_s[i] = 0.0f;

  const int lane = tid & 63;
  const int wv = tid >> 6;
  const int j = (wv & 7) * 64 + lane;
  const int kh = wv >> 3;

  float4 w4[16];
  {
    const float4* wr = (const float4*)(Whh + j * 128 + kh * 64);
#pragma unroll
    for (int q = 0; q < 16; q++) w4[q] = wr[q];
  }
  float wi0 = 0, wi1 = 0, wi2 = 0, wi3 = 0, wi4 = 0, wi5 = 0, bj = 0;
  if (kh == 0) {
    wi0 = Wih[j * 6 + 0]; wi1 = Wih[j * 6 + 1]; wi2 = Wih[j * 6 + 2];
    wi3 = Wih[j * 6 + 3]; wi4 = Wih[j * 6 + 4]; wi5 = Wih[j * 6 + 5];
    bj = bih[j] + bhh[j];
  }

  float c0 = 0.0f, c1 = 0.0f;
  const int p0m = tid >> 7;
  const int pn = tid & 127;

  __syncthreads();

  for (int t = 0; t < 40; t++) {
#pragma unroll 1
    for (int m = 0; m < 12; m++) {
      float acc;
      if (kh == 0) {
        const float* xm = Xs + (size_t)(s0 + m) * 240 + t * 6;
        acc = bj;
        acc = fmaf(wi0, xm[0], acc); acc = fmaf(wi1, xm[1], acc);
        acc = fmaf(wi2, xm[2], acc); acc = fmaf(wi3, xm[3], acc);
        acc = fmaf(wi4, xm[4], acc); acc = fmaf(wi5, xm[5], acc);
      } else {
        acc = 0.0f;
      }
      const float4* hp = (const float4*)(h_s + m * 128 + kh * 64);
#pragma unroll
      for (int q = 0; q < 16; q++) {
        float4 h4 = hp[q];
        acc = fmaf(w4[q].x, h4.x, acc);
        acc = fmaf(w4[q].y, h4.y, acc);
        acc = fmaf(w4[q].z, h4.z, acc);
        acc = fmaf(w4[q].w, h4.w, acc);
      }
      P[(kh * 12 + m) * 512 + j] = acc;
    }
    __syncthreads();
    {
      const int m = p0m, n = pn;
      const float* Pa = P + m * 512;
      const float* Pb = P + (12 + m) * 512;
      float gi = Pa[n] + Pb[n];
      float gf = Pa[n + 128] + Pb[n + 128];
      float gg = Pa[n + 256] + Pb[n + 256];
      float go = Pa[n + 384] + Pb[n + 384];
      c0 = sigm(gf) * c0 + sigm(gi) * tanhf(gg);
      float h = sigm(go) * tanhf(c0);
      h_s[m * 128 + n] = h;
      if (t >= 30) H10[((size_t)(s0 + m) * 10 + (t - 30)) * 128 + n] = h;
    }
    if (tid < 512) {
      const int m = 8 + p0m, n = pn;
      const float* Pa = P + m * 512;
      const float* Pb = P + (12 + m) * 512;
      float gi = Pa[n] + Pb[n];
      float gf = Pa[n + 128] + Pb[n + 128];
      float gg = Pa[n + 256] + Pb[n + 256];
      float go = Pa[n + 384] + Pb[n + 384];
      c1 = sigm(gf) * c1 + sigm(gi) * tanhf(gg);
      float h = sigm(go) * tanhf(c1);
      h_s[m * 128 + n] = h;
      if (t >= 30) H10[((size_t)(s0 + m) * 10 + (t - 30)) * 128 + n] = h;
    }
    __syncthreads();
  }
}

// ---------------------------------------------------------------------------
// Kernel 2a: LayerNorm in-place (unchanged).
// ---------------------------------------------------------------------------
__global__ __launch_bounds__(256) void ln_kernel(
    float* __restrict__ H, const float* __restrict__ g,
    const float* __restrict__ b, int nrows)
{
  int row = blockIdx.x * 4 + (threadIdx.x >> 6);
  int lane = threadIdx.x & 63;
  if (row >= nrows) return;
  float* hr = H + (size_t)row * 128;
  float x0 = hr[lane], x1 = hr[lane + 64];
  float s = x0 + x1;
  for (int off = 32; off > 0; off >>= 1) s += __shfl_xor(s, off);
  float mean = s * (1.0f / 128.0f);
  float d0 = x0 - mean, d1 = x1 - mean;
  float v = d0 * d0 + d1 * d1;
  for (int off = 32; off > 0; off >>= 1) v += __shfl_xor(v, off);
  float rstd = 1.0f / sqrtf(v * (1.0f / 128.0f) + 1e-5f);
  hr[lane] = d0 * rstd * g[lane] + b[lane];
  hr[lane + 64] = d1 * rstd * g[lane + 64] + b[lane + 64];
}

// ---------------------------------------------------------------------------
// Kernel 2b: Out[r] = l2norm(In_row[r] @ W^T) (unchanged).
// ---------------------------------------------------------------------------
__global__ __launch_bounds__(256) void proj_kernel(
    const float* __restrict__ In, int inOff, int inStride, int nr,
    const float* __restrict__ W, float* __restrict__ Out)
{
  __shared__ float A_s[16 * 128];
  const int tid = threadIdx.x;
  const int r0 = blockIdx.x * 16;

  for (int i = tid; i < 16 * 32; i += 256) {
    int row = i >> 5, c = i & 31;
    int gr = r0 + row;
    float4 v = make_float4(0.f, 0.f, 0.f, 0.f);
    if (gr < nr)
      v = *(const float4*)(In + (size_t)inOff + (size_t)gr * inStride + c * 4);
    *(float4*)(A_s + row * 128 + c * 4) = v;
  }
  __syncthreads();

  const int j = tid & 127, rh = tid >> 7;
  const float* wrow = W + j * 128;
  float acc[8] = {0, 0, 0, 0, 0, 0, 0, 0};
  for (int kc = 0; kc < 32; kc++) {
    float4 wv4 = *(const float4*)(wrow + kc * 4);
#pragma unroll
    for (int i = 0; i < 8; i++) {
      float4 a4 = *(const float4*)(A_s + (rh * 8 + i) * 128 + kc * 4);
      acc[i] = fmaf(wv4.x, a4.x, acc[i]);
      acc[i] = fmaf(wv4.y, a4.y, acc[i]);
      acc[i] = fmaf(wv4.z, a4.z, acc[i]);
      acc[i] = fmaf(wv4.w, a4.w, acc[i]);
    }
  }
  __syncthreads();
#pragma unroll
  for (int i = 0; i < 8; i++) A_s[(rh * 8 + i) * 128 + j] = acc[i];
  __syncthreads();

  const int r = tid >> 4, qq = tid & 15;
  float ss = 0.0f;
#pragma unroll
  for (int i = 0; i < 8; i++) {
    float u = A_s[r * 128 + qq + i * 16];
    ss += u * u;
  }
  for (int off = 8; off > 0; off >>= 1) ss += __shfl_xor(ss, off);
  float scale = 1.0f / fmaxf(sqrtf(ss), 1e-12f);
  int gr = r0 + r;
  if (gr < nr) {
#pragma unroll
    for (int i = 0; i < 8; i++)
      Out[(size_t)gr * 128 + qq + i * 16] = A_s[r * 128 + qq + i * 16] * scale;
  }
}

// ---------------------------------------------------------------------------
// Kernel 2c: fp32 -> (bf16 hi, bf16 lo) split, vectorized x4.
// ---------------------------------------------------------------------------
__global__ __launch_bounds__(256) void cvt_kernel(
    const float* __restrict__ src, unsigned short* __restrict__ hi,
    unsigned short* __restrict__ lo, int n4)
{
  int i = blockIdx.x * 256 + threadIdx.x;
  if (i >= n4) return;
  float4 f = ((const float4*)src)[i];
  ushort4 h, l;
  h.x = f2bf_rne(f.x); l.x = f2bf_rne(f.x - bf2f(h.x));
  h.y = f2bf_rne(f.y); l.y = f2bf_rne(f.y - bf2f(h.y));
  h.z = f2bf_rne(f.z); l.z = f2bf_rne(f.z - bf2f(h.z));
  h.w = f2bf_rne(f.w); l.w = f2bf_rne(f.w - bf2f(h.w));
  ((ushort4*)hi)[i] = h;
  ((ushort4*)lo)[i] = l;
}

// ---------------------------------------------------------------------------
// Kernel 3: MFMA score + per-chunk approx top-8.
// grid (94 tgt-blocks, 16 chunks) x 256 threads (4 waves).
// Per wave: 32x32 tile (targets x cands), K=128 via 8 MFMA steps x3 (bf16 x3
// split: hi*hi + hi*lo + lo*hi; |err| <= ~2^-17/temp, margin-covered by top-8
// + exact rescore in final_kernel). B (gathered Q rows) persistent in VGPRs;
// A (K rows) streamed from L2 into fragments — no LDS in the GEMM.
// C/D layout (HW-verified): col(target)=lane&31, row(cand)=(reg&3)+8*(reg>>2)
// +4*(lane>>5). A/B k-permutation self-consistency makes the dot exact wrt
// any lane->k convention.
// ---------------------------------------------------------------------------
__global__ __launch_bounds__(256, 3) void score_mfma(
    const unsigned short* __restrict__ Qh, const unsigned short* __restrict__ Ql,
    const unsigned short* __restrict__ Kh, const unsigned short* __restrict__ Kl,
    const int* __restrict__ tix, const float* __restrict__ log_temp,
    const float* __restrict__ lag_bias, float* __restrict__ part)
{
  __shared__ float lagS[16];
  __shared__ float M[256 * 16];   // per-lane top-8 dump for the merge
  const int tid = threadIdx.x;
  const int wv = tid >> 6, lane = tid & 63;
  const int half = lane >> 5, tcol = lane & 31;
  const int chunk = blockIdx.y;
  const int T0 = blockIdx.x * 32;
  const int colBase = chunk * SC_COLS;
  const int colEnd = colBase + SC_COLS;   // SCHUNK*SC_COLS == NCOLS exactly

  if (tid < 10) lagS[tid] = lag_bias[tid];

  const int tgt = T0 + tcol;
  const int tgtc = tgt < S_N ? tgt : S_N - 1;
  const int myTix = tix[tgtc];
  const float invtemp =
      1.0f / fminf(fmaxf(expf(log_temp[0]), 0.1f), 11.313708499f);

  // persistent B fragments: 8 k-steps x (hi,lo), 64 VGPRs
  v8bf bh[8], bl[8];
  {
    const size_t qo = (size_t)myTix * 128 + half * 8;
#pragma unroll
    for (int s = 0; s < 8; s++) {
      bh[s] = *(const v8bf*)(Qh + qo + s * 16);
      bl[s] = *(const v8bf*)(Ql + qo + s * 16);
    }
  }

  float tv[8]; int ti[8];
#pragma unroll
  for (int q = 0; q < 8; q++) { tv[q] = -3e38f; ti[q] = 0x7fffffff; }

  __syncthreads();   // lagS ready

  const int niter = (SC_COLS + 127) / 128;   // 15
  for (int it = 0; it < niter; it++) {
    const int cb = colBase + it * 128 + wv * 32;
    const int arow = cb + tcol;
    const int arowc = arow < NCOLS ? arow : NCOLS - 1;
    const size_t ao = (size_t)arowc * 128 + half * 8;

    v16f acc0, acc1;
#pragma unroll
    for (int q = 0; q < 16; q++) { acc0[q] = 0.0f; acc1[q] = 0.0f; }

#pragma unroll
    for (int s = 0; s < 8; s++) {
      v8bf ah = *(const v8bf*)(Kh + ao + s * 16);
      v8bf al = *(const v8bf*)(Kl + ao + s * 16);
      acc0 = __builtin_amdgcn_mfma_f32_32x32x16_bf16(ah, bh[s], acc0, 0, 0, 0);
      acc1 = __builtin_amdgcn_mfma_f32_32x32x16_bf16(ah, bl[s], acc1, 0, 0, 0);
      acc1 = __builtin_amdgcn_mfma_f32_32x32x16_bf16(al, bh[s], acc1, 0, 0, 0);
    }

#pragma unroll
    for (int reg = 0; reg < 16; reg++) {
      const int row = (reg & 3) + 8 * (reg >> 2) + 4 * half;
      const int col = cb + row;   // ascending in reg; ascending across iters
      if (col < colEnd) {
        const int s = col / 10;
        const int lag = col - s * 10;
        if (s != myTix) {
          float vsc = (acc0[reg] + acc1[reg]) * invtemp + lagS[lag];
          insS<8>(tv, ti, vsc, col);
        }
      }
    }
  }

  // ---- merge 8 lane-lists (4 waves x 2 halves) per target ----
  {
    float* my = M + tid * 16;
#pragma unroll
    for (int q = 0; q < 8; q++) {
      my[2 * q] = tv[q];
      my[2 * q + 1] = __int_as_float(ti[q]);
    }
  }
  __syncthreads();
  if (tid < 32 && T0 + tid < S_N) {
    float v[8]; int ix[8];
#pragma unroll
    for (int q = 0; q < 8; q++) { v[q] = -3e38f; ix[q] = 0x7fffffff; }
    for (int w = 0; w < 8; w++) {
      const float* src = M + (w * 32 + tid) * 16;
#pragma unroll
      for (int q = 0; q < 8; q++)
        insF<8>(v, ix, src[2 * q], __float_as_int(src[2 * q + 1]));
    }
    float* dst = part + ((size_t)(T0 + tid) * SCHUNK + chunk) * 16;
#pragma unroll
    for (int q = 0; q < 8; q++) {
      dst[2 * q] = v[q];
      dst[2 * q + 1] = __int_as_float(ix[q]);
    }
  }
}

// ---------------------------------------------------------------------------
// Kernel 4: merge 16 chunks x approx-top-8 -> approx top-8, exact fp32
// rescore -> exact top-5 -> softmax -> gather z -> MLP.
// ---------------------------------------------------------------------------
__global__ __launch_bounds__(256) void final_kernel(
    const float* __restrict__ part, const float* __restrict__ Qn,
    const float* __restrict__ Kn, const int* __restrict__ tix,
    const float* __restrict__ log_temp, const float* __restrict__ lag_bias,
    const float* __restrict__ Xraw,
    const float* __restrict__ W1, const float* __restrict__ b1,
    const float* __restrict__ W2, const float* __restrict__ b2,
    const float* __restrict__ W3, const float* __restrict__ b3,
    float* __restrict__ out)
{
  __shared__ float W1s[64 * 12];
  __shared__ float W2s[32 * 64];
  __shared__ float b1s[64];
  __shared__ float b2s[32];
  __shared__ float W3s[32];
  const int tid = threadIdx.x;
  for (int i = tid; i < 768; i += 256) W1s[i] = W1[i];
  for (int i = tid; i < 2048; i += 256) W2s[i] = W2[i];
  if (tid < 64) b1s[tid] = b1[tid];
  if (tid < 32) { b2s[tid] = b2[tid]; W3s[tid] = W3[tid]; }
  __syncthreads();

  int t = blockIdx.x * 256 + tid;
  if (t >= S_N) return;

  // ---- approx global top-8 from 16 x 8 chunk entries ----
  float av[8]; int ai[8];
#pragma unroll
  for (int q = 0; q < 8; q++) { av[q] = -3e38f; ai[q] = 0x7fffffff; }
  const float* pp = part + (size_t)t * (SCHUNK * 16);
  for (int c = 0; c < SCHUNK * 8; c++)
    insF<8>(av, ai, pp[2 * c], __float_as_int(pp[2 * c + 1]));

  // ---- exact fp32 rescore of the 8 survivors ----
  const float invtemp =
      1.0f / fminf(fmaxf(expf(log_temp[0]), 0.1f), 11.313708499f);
  const float* q = Qn + (size_t)tix[t] * 128;
  const float* kr[8];
#pragma unroll
  for (int j = 0; j < 8; j++) kr[j] = Kn + (size_t)ai[j] * 128;
  float d[8] = {0, 0, 0, 0, 0, 0, 0, 0};
  for (int kc = 0; kc < 32; kc++) {
    float4 q4 = ((const float4*)q)[kc];
#pragma unroll
    for (int j = 0; j < 8; j++) {
      float4 k4 = ((const float4*)kr[j])[kc];
      d[j] = fmaf(q4.x, k4.x, d[j]);
      d[j] = fmaf(q4.y, k4.y, d[j]);
      d[j] = fmaf(q4.z, k4.z, d[j]);
      d[j] = fmaf(q4.w, k4.w, d[j]);
    }
  }

  float v[5]; int ix[5];
#pragma unroll
  for (int qq = 0; qq < 5; qq++) { v[qq] = -3e38f; ix[qq] = 0x7fffffff; }
#pragma unroll
  for (int j = 0; j < 8; j++) {
    int c = ai[j];
    int s = c / 10;
    int lag = c - 10 * s;
    float ev = d[j] * invtemp + lag_bias[lag];
    insF<5>(v, ix, ev, c);
  }

  // ---- softmax over exact vals; v[0] is max by construction ----
  float e1 = expf(v[1] - v[0]), e2 = expf(v[2] - v[0]),
        e3 = expf(v[3] - v[0]), e4 = expf(v[4] - v[0]);
  float rs = 1.0f / (1.0f + e1 + e2 + e3 + e4);
  float w_[5] = {rs, e1 * rs, e2 * rs, e3 * rs, e4 * rs};

  float feat[12];
#pragma unroll
  for (int f = 0; f < 12; f++) feat[f] = 0.0f;
#pragma unroll
  for (int qq = 0; qq < 5; qq++) {
    int iq = ix[qq];
    int s = iq / 10;
    int l = iq - 10 * s;
    int pos = 29 + l;   // clip(L-1-(L_MAX-l), 0, L-1)
    const float* zp = Xraw + (size_t)s * 240 + pos * 6;
#pragma unroll
    for (int f = 0; f < 6; f++) {
      float z = zp[f];
      feat[f] += w_[qq] * z;
      if (qq == 0) feat[6 + f] = z;
    }
  }

  float h1[64];
#pragma unroll 4
  for (int o = 0; o < 64; o++) {
    float acc = b1s[o];
    const float* wr = W1s + o * 12;
#pragma unroll
    for (int f = 0; f < 12; f++) acc = fmaf(wr[f], feat[f], acc);
    h1[o] = fmaxf(acc, 0.0f);
  }
  float rr = b3[0];
#pragma unroll 2
  for (int o = 0; o < 32; o++) {
    float acc = b2s[o];
    const float* wr = W2s + o * 64;
#pragma unroll 8
    for (int k = 0; k < 64; k++) acc = fmaf(wr[k], h1[k], acc);
    rr = fmaf(W3s[o], fmaxf(acc, 0.0f), rr);
  }
  out[t] = rr;
}

// ---------------------------------------------------------------------------
extern "C" void kernel_launch(void* const* d_in, const int* in_sizes, int n_in,
                              void* d_out, int out_size, void* d_ws,
                              size_t ws_size, hipStream_t stream) {
  const float* Xs   = (const float*)d_in[0];
  const float* Xraw = (const float*)d_in[1];
  const int*   tix  = (const int*)d_in[2];
  const float* Wih  = (const float*)d_in[3];
  const float* Whh  = (const float*)d_in[4];
  const float* bih  = (const float*)d_in[5];
  const float* bhh  = (const float*)d_in[6];
  const float* ln_g = (const float*)d_in[7];
  const float* ln_b = (const float*)d_in[8];
  const float* WQ   = (const float*)d_in[9];
  const float* WK   = (const float*)d_in[10];
  const float* log_temp = (const float*)d_in[11];
  const float* lag_bias = (const float*)d_in[12];
  const float* W1 = (const float*)d_in[13];
  const float* b1 = (const float*)d_in[14];
  const float* W2 = (const float*)d_in[15];
  const float* b2 = (const float*)d_in[16];
  const float* W3 = (const float*)d_in[17];
  const float* b3 = (const float*)d_in[18];
  float* outp = (float*)d_out;

  float* ws = (float*)d_ws;
  // ws layout (floats). H10 is dead after the proj kernels; K_hi/K_lo overlay
  // it (cvt runs strictly after both projs). Max footprint 9.216M fl = 36.9 MB.
  float* H10 = ws;                                         // [0, 3.84M)
  unsigned short* Khi = (unsigned short*)ws;               // overlays H10
  unsigned short* Klo = (unsigned short*)(ws + 1920000);
  float* Kn  = ws + 3840000;                               // [3.84M, 7.68M)
  float* Qn  = ws + 7680000;                               // [7.68M, 8.064M)
  unsigned short* Qhi = (unsigned short*)(ws + 8064000);
  unsigned short* Qlo = (unsigned short*)(ws + 8256000);
  float* part = ws + 8448000;                              // 3000*16*16 = 768k

  lstm_kernel<<<250, 1024, 0, stream>>>(Xs, Wih, Whh, bih, bhh, H10);
  ln_kernel<<<7500, 256, 0, stream>>>(H10, ln_g, ln_b, 30000);
  proj_kernel<<<1875, 256, 0, stream>>>(H10, 0, 128, 30000, WK, Kn);
  proj_kernel<<<188, 256, 0, stream>>>(H10, 9 * 128, 1280, 3000, WQ, Qn);
  cvt_kernel<<<3750, 256, 0, stream>>>(Kn, Khi, Klo, 960000);
  cvt_kernel<<<375, 256, 0, stream>>>(Qn, Qhi, Qlo, 96000);
  {
    dim3 grid(94, SCHUNK);
    score_mfma<<<grid, 256, 0, stream>>>(Qhi, Qlo, Khi, Klo, tix, log_temp,
                                         lag_bias, part);
  }
  final_kernel<<<12, 256, 0, stream>>>(part, Qn, Kn, tix, log_temp, lag_bias,
                                       Xraw, W1, b1, W2, b2, W3, b3, outp);
}

// Round 5
// 942.137 us; speedup vs baseline: 1.3930x; 1.0063x over previous
//
#include <hip/hip_runtime.h>
#include <math.h>

#define S_N 3000
#define NCOLS 30000
#define SCHUNK 16
#define SC_COLS 1875    // 30000/16

typedef __bf16 v8bf __attribute__((ext_vector_type(8)));
typedef float v16f __attribute__((ext_vector_type(16)));

__device__ __forceinline__ float sigm(float x) { return 1.0f / (1.0f + expf(-x)); }

__device__ __forceinline__ bool bet(float av, int ai, float bv, int bi) {
  return (av > bv) || (av == bv && ai < bi);
}

// streaming insert (candidates ascending by index): strict > == lax.top_k tie rule
template <int M>
__device__ __forceinline__ void insS(float (&v)[M], int (&ix)[M], float nv, int ni) {
  if (!(nv > v[M - 1])) return;
  bool b[M];
#pragma unroll
  for (int q = 0; q < M; q++) b[q] = nv > v[q];
#pragma unroll
  for (int q = M - 1; q > 0; q--) {
    v[q]  = b[q] ? (b[q - 1] ? v[q - 1] : nv) : v[q];
    ix[q] = b[q] ? (b[q - 1] ? ix[q - 1] : ni) : ix[q];
  }
  if (b[0]) { v[0] = nv; ix[0] = ni; }
}

// full comparator insert (value desc, index asc) for arbitrary-order merges
template <int M>
__device__ __forceinline__ void insF(float (&v)[M], int (&ix)[M], float nv, int ni) {
  if (!bet(nv, ni, v[M - 1], ix[M - 1])) return;
  bool b[M];
#pragma unroll
  for (int q = 0; q < M; q++) b[q] = bet(nv, ni, v[q], ix[q]);
#pragma unroll
  for (int q = M - 1; q > 0; q--) {
    v[q]  = b[q] ? (b[q - 1] ? v[q - 1] : nv) : v[q];
    ix[q] = b[q] ? (b[q - 1] ? ix[q - 1] : ni) : ix[q];
  }
  if (b[0]) { v[0] = nv; ix[0] = ni; }
}

__device__ __forceinline__ unsigned short f2bf_rne(float f) {
  unsigned int u = __float_as_uint(f);
  unsigned int r = (u + 0x7fffu + ((u >> 16) & 1u)) >> 16;
  return (unsigned short)r;
}
__device__ __forceinline__ float bf2f(unsigned short h) {
  return __uint_as_float(((unsigned int)h) << 16);
}

// ---------------------------------------------------------------------------
// Kernel 1: LSTM. 250 blocks x 1024 threads; each block owns 12 sequences.
// Each lane holds Whh[j][kh*64 .. kh*64+63] stationary in 64 VGPRs.
// The inline-asm pin after the preload makes w4 opaque so the compiler
// CANNOT rematerialize the loads inside the loop (R4: VGPR=56 proved it did).
// ---------------------------------------------------------------------------
__global__ __launch_bounds__(1024, 4) void lstm_kernel(
    const float* __restrict__ Xs, const float* __restrict__ Wih,
    const float* __restrict__ Whh, const float* __restrict__ bih,
    const float* __restrict__ bhh, float* __restrict__ H10)
{
  __shared__ float h_s[12 * 128];
  __shared__ float P[2 * 12 * 512];
  const int tid = threadIdx.x;
  const int s0 = blockIdx.x * 12;

  for (int i = tid; i < 12 * 128; i += 1024) h_s[i] = 0.0f;

  const int lane = tid & 63;
  const int wv = tid >> 6;
  const int j = (wv & 7) * 64 + lane;
  const int kh = wv >> 3;

  float4 w4[16];
  {
    const float4* wr = (const float4*)(Whh + j * 128 + kh * 64);
#pragma unroll
    for (int q = 0; q < 16; q++) w4[q] = wr[q];
  }
  // pin: forbid rematerialization of the weight loads
#pragma unroll
  for (int q = 0; q < 16; q++) {
    asm volatile("" : "+v"(w4[q].x), "+v"(w4[q].y), "+v"(w4[q].z),
                      "+v"(w4[q].w));
  }

  float wi0 = 0, wi1 = 0, wi2 = 0, wi3 = 0, wi4 = 0, wi5 = 0, bj = 0;
  if (kh == 0) {
    wi0 = Wih[j * 6 + 0]; wi1 = Wih[j * 6 + 1]; wi2 = Wih[j * 6 + 2];
    wi3 = Wih[j * 6 + 3]; wi4 = Wih[j * 6 + 4]; wi5 = Wih[j * 6 + 5];
    bj = bih[j] + bhh[j];
  }

  float c0 = 0.0f, c1 = 0.0f;
  const int p0m = tid >> 7;
  const int pn = tid & 127;

  __syncthreads();

  for (int t = 0; t < 40; t++) {
#pragma unroll 1
    for (int m = 0; m < 12; m++) {
      float acc;
      if (kh == 0) {
        const float* xm = Xs + (size_t)(s0 + m) * 240 + t * 6;
        acc = bj;
        acc = fmaf(wi0, xm[0], acc); acc = fmaf(wi1, xm[1], acc);
        acc = fmaf(wi2, xm[2], acc); acc = fmaf(wi3, xm[3], acc);
        acc = fmaf(wi4, xm[4], acc); acc = fmaf(wi5, xm[5], acc);
      } else {
        acc = 0.0f;
      }
      const float4* hp = (const float4*)(h_s + m * 128 + kh * 64);
#pragma unroll
      for (int q = 0; q < 16; q++) {
        float4 h4 = hp[q];
        acc = fmaf(w4[q].x, h4.x, acc);
        acc = fmaf(w4[q].y, h4.y, acc);
        acc = fmaf(w4[q].z, h4.z, acc);
        acc = fmaf(w4[q].w, h4.w, acc);
      }
      P[(kh * 12 + m) * 512 + j] = acc;
    }
    __syncthreads();
    {
      const int m = p0m, n = pn;
      const float* Pa = P + m * 512;
      const float* Pb = P + (12 + m) * 512;
      float gi = Pa[n] + Pb[n];
      float gf = Pa[n + 128] + Pb[n + 128];
      float gg = Pa[n + 256] + Pb[n + 256];
      float go = Pa[n + 384] + Pb[n + 384];
      c0 = sigm(gf) * c0 + sigm(gi) * tanhf(gg);
      float h = sigm(go) * tanhf(c0);
      h_s[m * 128 + n] = h;
      if (t >= 30) H10[((size_t)(s0 + m) * 10 + (t - 30)) * 128 + n] = h;
    }
    if (tid < 512) {
      const int m = 8 + p0m, n = pn;
      const float* Pa = P + m * 512;
      const float* Pb = P + (12 + m) * 512;
      float gi = Pa[n] + Pb[n];
      float gf = Pa[n + 128] + Pb[n + 128];
      float gg = Pa[n + 256] + Pb[n + 256];
      float go = Pa[n + 384] + Pb[n + 384];
      c1 = sigm(gf) * c1 + sigm(gi) * tanhf(gg);
      float h = sigm(go) * tanhf(c1);
      h_s[m * 128 + n] = h;
      if (t >= 30) H10[((size_t)(s0 + m) * 10 + (t - 30)) * 128 + n] = h;
    }
    __syncthreads();
  }
}

// ---------------------------------------------------------------------------
// Kernel 2a: LayerNorm in-place (unchanged).
// ---------------------------------------------------------------------------
__global__ __launch_bounds__(256) void ln_kernel(
    float* __restrict__ H, const float* __restrict__ g,
    const float* __restrict__ b, int nrows)
{
  int row = blockIdx.x * 4 + (threadIdx.x >> 6);
  int lane = threadIdx.x & 63;
  if (row >= nrows) return;
  float* hr = H + (size_t)row * 128;
  float x0 = hr[lane], x1 = hr[lane + 64];
  float s = x0 + x1;
  for (int off = 32; off > 0; off >>= 1) s += __shfl_xor(s, off);
  float mean = s * (1.0f / 128.0f);
  float d0 = x0 - mean, d1 = x1 - mean;
  float v = d0 * d0 + d1 * d1;
  for (int off = 32; off > 0; off >>= 1) v += __shfl_xor(v, off);
  float rstd = 1.0f / sqrtf(v * (1.0f / 128.0f) + 1e-5f);
  hr[lane] = d0 * rstd * g[lane] + b[lane];
  hr[lane + 64] = d1 * rstd * g[lane + 64] + b[lane + 64];
}

// ---------------------------------------------------------------------------
// Kernel 2b: Out[r] = l2norm(In_row[r] @ W^T) (unchanged).
// ---------------------------------------------------------------------------
__global__ __launch_bounds__(256) void proj_kernel(
    const float* __restrict__ In, int inOff, int inStride, int nr,
    const float* __restrict__ W, float* __restrict__ Out)
{
  __shared__ float A_s[16 * 128];
  const int tid = threadIdx.x;
  const int r0 = blockIdx.x * 16;

  for (int i = tid; i < 16 * 32; i += 256) {
    int row = i >> 5, c = i & 31;
    int gr = r0 + row;
    float4 v = make_float4(0.f, 0.f, 0.f, 0.f);
    if (gr < nr)
      v = *(const float4*)(In + (size_t)inOff + (size_t)gr * inStride + c * 4);
    *(float4*)(A_s + row * 128 + c * 4) = v;
  }
  __syncthreads();

  const int j = tid & 127, rh = tid >> 7;
  const float* wrow = W + j * 128;
  float acc[8] = {0, 0, 0, 0, 0, 0, 0, 0};
  for (int kc = 0; kc < 32; kc++) {
    float4 wv4 = *(const float4*)(wrow + kc * 4);
#pragma unroll
    for (int i = 0; i < 8; i++) {
      float4 a4 = *(const float4*)(A_s + (rh * 8 + i) * 128 + kc * 4);
      acc[i] = fmaf(wv4.x, a4.x, acc[i]);
      acc[i] = fmaf(wv4.y, a4.y, acc[i]);
      acc[i] = fmaf(wv4.z, a4.z, acc[i]);
      acc[i] = fmaf(wv4.w, a4.w, acc[i]);
    }
  }
  __syncthreads();
#pragma unroll
  for (int i = 0; i < 8; i++) A_s[(rh * 8 + i) * 128 + j] = acc[i];
  __syncthreads();

  const int r = tid >> 4, qq = tid & 15;
  float ss = 0.0f;
#pragma unroll
  for (int i = 0; i < 8; i++) {
    float u = A_s[r * 128 + qq + i * 16];
    ss += u * u;
  }
  for (int off = 8; off > 0; off >>= 1) ss += __shfl_xor(ss, off);
  float scale = 1.0f / fmaxf(sqrtf(ss), 1e-12f);
  int gr = r0 + r;
  if (gr < nr) {
#pragma unroll
    for (int i = 0; i < 8; i++)
      Out[(size_t)gr * 128 + qq + i * 16] = A_s[r * 128 + qq + i * 16] * scale;
  }
}

// ---------------------------------------------------------------------------
// Kernel 2c: fp32 -> (bf16 hi, bf16 lo) split, vectorized x4 (unchanged).
// ---------------------------------------------------------------------------
__global__ __launch_bounds__(256) void cvt_kernel(
    const float* __restrict__ src, unsigned short* __restrict__ hi,
    unsigned short* __restrict__ lo, int n4)
{
  int i = blockIdx.x * 256 + threadIdx.x;
  if (i >= n4) return;
  float4 f = ((const float4*)src)[i];
  ushort4 h, l;
  h.x = f2bf_rne(f.x); l.x = f2bf_rne(f.x - bf2f(h.x));
  h.y = f2bf_rne(f.y); l.y = f2bf_rne(f.y - bf2f(h.y));
  h.z = f2bf_rne(f.z); l.z = f2bf_rne(f.z - bf2f(h.z));
  h.w = f2bf_rne(f.w); l.w = f2bf_rne(f.w - bf2f(h.w));
  ((ushort4*)hi)[i] = h;
  ((ushort4*)lo)[i] = l;
}

// ---------------------------------------------------------------------------
// Kernel 3: MFMA score + per-chunk approx top-8 (R4 structure + asm pin on
// the persistent B fragments so they can't be rematerialized per tile).
// ---------------------------------------------------------------------------
__global__ __launch_bounds__(256, 3) void score_mfma(
    const unsigned short* __restrict__ Qh, const unsigned short* __restrict__ Ql,
    const unsigned short* __restrict__ Kh, const unsigned short* __restrict__ Kl,
    const int* __restrict__ tix, const float* __restrict__ log_temp,
    const float* __restrict__ lag_bias, float* __restrict__ part)
{
  __shared__ float lagS[16];
  __shared__ float M[256 * 16];
  const int tid = threadIdx.x;
  const int wv = tid >> 6, lane = tid & 63;
  const int half = lane >> 5, tcol = lane & 31;
  const int chunk = blockIdx.y;
  const int T0 = blockIdx.x * 32;
  const int colBase = chunk * SC_COLS;
  const int colEnd = colBase + SC_COLS;

  if (tid < 10) lagS[tid] = lag_bias[tid];

  const int tgt = T0 + tcol;
  const int tgtc = tgt < S_N ? tgt : S_N - 1;
  const int myTix = tix[tgtc];
  const float invtemp =
      1.0f / fminf(fmaxf(expf(log_temp[0]), 0.1f), 11.313708499f);

  // persistent B fragments: 8 k-steps x (hi,lo), 64 VGPRs
  v8bf bh[8], bl[8];
  {
    const size_t qo = (size_t)myTix * 128 + half * 8;
#pragma unroll
    for (int s = 0; s < 8; s++) {
      bh[s] = *(const v8bf*)(Qh + qo + s * 16);
      bl[s] = *(const v8bf*)(Ql + qo + s * 16);
    }
  }
  // pin: forbid rematerialization of the Q-fragment loads
#pragma unroll
  for (int s = 0; s < 8; s++) {
    asm volatile("" : "+v"(bh[s]), "+v"(bl[s]));
  }

  float tv[8]; int ti[8];
#pragma unroll
  for (int q = 0; q < 8; q++) { tv[q] = -3e38f; ti[q] = 0x7fffffff; }

  __syncthreads();   // lagS ready

  const int niter = (SC_COLS + 127) / 128;   // 15
  for (int it = 0; it < niter; it++) {
    const int cb = colBase + it * 128 + wv * 32;
    const int arow = cb + tcol;
    const int arowc = arow < NCOLS ? arow : NCOLS - 1;
    const size_t ao = (size_t)arowc * 128 + half * 8;

    v16f acc0, acc1;
#pragma unroll
    for (int q = 0; q < 16; q++) { acc0[q] = 0.0f; acc1[q] = 0.0f; }

#pragma unroll
    for (int s = 0; s < 8; s++) {
      v8bf ah = *(const v8bf*)(Kh + ao + s * 16);
      v8bf al = *(const v8bf*)(Kl + ao + s * 16);
      acc0 = __builtin_amdgcn_mfma_f32_32x32x16_bf16(ah, bh[s], acc0, 0, 0, 0);
      acc1 = __builtin_amdgcn_mfma_f32_32x32x16_bf16(ah, bl[s], acc1, 0, 0, 0);
      acc1 = __builtin_amdgcn_mfma_f32_32x32x16_bf16(al, bh[s], acc1, 0, 0, 0);
    }

#pragma unroll
    for (int reg = 0; reg < 16; reg++) {
      const int row = (reg & 3) + 8 * (reg >> 2) + 4 * half;
      const int col = cb + row;
      if (col < colEnd) {
        const int s = col / 10;
        const int lag = col - s * 10;
        if (s != myTix) {
          float vsc = (acc0[reg] + acc1[reg]) * invtemp + lagS[lag];
          insS<8>(tv, ti, vsc, col);
        }
      }
    }
  }

  // ---- merge 8 lane-lists (4 waves x 2 halves) per target ----
  {
    float* my = M + tid * 16;
#pragma unroll
    for (int q = 0; q < 8; q++) {
      my[2 * q] = tv[q];
      my[2 * q + 1] = __int_as_float(ti[q]);
    }
  }
  __syncthreads();
  if (tid < 32 && T0 + tid < S_N) {
    float v[8]; int ix[8];
#pragma unroll
    for (int q = 0; q < 8; q++) { v[q] = -3e38f; ix[q] = 0x7fffffff; }
    for (int w = 0; w < 8; w++) {
      const float* src = M + (w * 32 + tid) * 16;
#pragma unroll
      for (int q = 0; q < 8; q++)
        insF<8>(v, ix, src[2 * q], __float_as_int(src[2 * q + 1]));
    }
    float* dst = part + ((size_t)(T0 + tid) * SCHUNK + chunk) * 16;
#pragma unroll
    for (int q = 0; q < 8; q++) {
      dst[2 * q] = v[q];
      dst[2 * q + 1] = __int_as_float(ix[q]);
    }
  }
}

// ---------------------------------------------------------------------------
// Kernel 4: merge chunks -> approx top-8, exact fp32 rescore -> exact top-5,
// softmax, gather z, MLP (unchanged).
// ---------------------------------------------------------------------------
__global__ __launch_bounds__(256) void final_kernel(
    const float* __restrict__ part, const float* __restrict__ Qn,
    const float* __restrict__ Kn, const int* __restrict__ tix,
    const float* __restrict__ log_temp, const float* __restrict__ lag_bias,
    const float* __restrict__ Xraw,
    const float* __restrict__ W1, const float* __restrict__ b1,
    const float* __restrict__ W2, const float* __restrict__ b2,
    const float* __restrict__ W3, const float* __restrict__ b3,
    float* __restrict__ out)
{
  __shared__ float W1s[64 * 12];
  __shared__ float W2s[32 * 64];
  __shared__ float b1s[64];
  __shared__ float b2s[32];
  __shared__ float W3s[32];
  const int tid = threadIdx.x;
  for (int i = tid; i < 768; i += 256) W1s[i] = W1[i];
  for (int i = tid; i < 2048; i += 256) W2s[i] = W2[i];
  if (tid < 64) b1s[tid] = b1[tid];
  if (tid < 32) { b2s[tid] = b2[tid]; W3s[tid] = W3[tid]; }
  __syncthreads();

  int t = blockIdx.x * 256 + tid;
  if (t >= S_N) return;

  float av[8]; int ai[8];
#pragma unroll
  for (int q = 0; q < 8; q++) { av[q] = -3e38f; ai[q] = 0x7fffffff; }
  const float* pp = part + (size_t)t * (SCHUNK * 16);
  for (int c = 0; c < SCHUNK * 8; c++)
    insF<8>(av, ai, pp[2 * c], __float_as_int(pp[2 * c + 1]));

  const float invtemp =
      1.0f / fminf(fmaxf(expf(log_temp[0]), 0.1f), 11.313708499f);
  const float* q = Qn + (size_t)tix[t] * 128;
  const float* kr[8];
#pragma unroll
  for (int j = 0; j < 8; j++) kr[j] = Kn + (size_t)ai[j] * 128;
  float d[8] = {0, 0, 0, 0, 0, 0, 0, 0};
  for (int kc = 0; kc < 32; kc++) {
    float4 q4 = ((const float4*)q)[kc];
#pragma unroll
    for (int j = 0; j < 8; j++) {
      float4 k4 = ((const float4*)kr[j])[kc];
      d[j] = fmaf(q4.x, k4.x, d[j]);
      d[j] = fmaf(q4.y, k4.y, d[j]);
      d[j] = fmaf(q4.z, k4.z, d[j]);
      d[j] = fmaf(q4.w, k4.w, d[j]);
    }
  }

  float v[5]; int ix[5];
#pragma unroll
  for (int qq = 0; qq < 5; qq++) { v[qq] = -3e38f; ix[qq] = 0x7fffffff; }
#pragma unroll
  for (int j = 0; j < 8; j++) {
    int c = ai[j];
    int s = c / 10;
    int lag = c - 10 * s;
    float ev = d[j] * invtemp + lag_bias[lag];
    insF<5>(v, ix, ev, c);
  }

  float e1 = expf(v[1] - v[0]), e2 = expf(v[2] - v[0]),
        e3 = expf(v[3] - v[0]), e4 = expf(v[4] - v[0]);
  float rs = 1.0f / (1.0f + e1 + e2 + e3 + e4);
  float w_[5] = {rs, e1 * rs, e2 * rs, e3 * rs, e4 * rs};

  float feat[12];
#pragma unroll
  for (int f = 0; f < 12; f++) feat[f] = 0.0f;
#pragma unroll
  for (int qq = 0; qq < 5; qq++) {
    int iq = ix[qq];
    int s = iq / 10;
    int l = iq - 10 * s;
    int pos = 29 + l;
    const float* zp = Xraw + (size_t)s * 240 + pos * 6;
#pragma unroll
    for (int f = 0; f < 6; f++) {
      float z = zp[f];
      feat[f] += w_[qq] * z;
      if (qq == 0) feat[6 + f] = z;
    }
  }

  float h1[64];
#pragma unroll 4
  for (int o = 0; o < 64; o++) {
    float acc = b1s[o];
    const float* wr = W1s + o * 12;
#pragma unroll
    for (int f = 0; f < 12; f++) acc = fmaf(wr[f], feat[f], acc);
    h1[o] = fmaxf(acc, 0.0f);
  }
  float rr = b3[0];
#pragma unroll 2
  for (int o = 0; o < 32; o++) {
    float acc = b2s[o];
    const float* wr = W2s + o * 64;
#pragma unroll 8
    for (int k = 0; k < 64; k++) acc = fmaf(wr[k], h1[k], acc);
    rr = fmaf(W3s[o], fmaxf(acc, 0.0f), rr);
  }
  out[t] = rr;
}

// ---------------------------------------------------------------------------
extern "C" void kernel_launch(void* const* d_in, const int* in_sizes, int n_in,
                              void* d_out, int out_size, void* d_ws,
                              size_t ws_size, hipStream_t stream) {
  const float* Xs   = (const float*)d_in[0];
  const float* Xraw = (const float*)d_in[1];
  const int*   tix  = (const int*)d_in[2];
  const float* Wih  = (const float*)d_in[3];
  const float* Whh  = (const float*)d_in[4];
  const float* bih  = (const float*)d_in[5];
  const float* bhh  = (const float*)d_in[6];
  const float* ln_g = (const float*)d_in[7];
  const float* ln_b = (const float*)d_in[8];
  const float* WQ   = (const float*)d_in[9];
  const float* WK   = (const float*)d_in[10];
  const float* log_temp = (const float*)d_in[11];
  const float* lag_bias = (const float*)d_in[12];
  const float* W1 = (const float*)d_in[13];
  const float* b1 = (const float*)d_in[14];
  const float* W2 = (const float*)d_in[15];
  const float* b2 = (const float*)d_in[16];
  const float* W3 = (const float*)d_in[17];
  const float* b3 = (const float*)d_in[18];
  float* outp = (float*)d_out;

  float* ws = (float*)d_ws;
  float* H10 = ws;                                         // [0, 3.84M)
  unsigned short* Khi = (unsigned short*)ws;               // overlays H10
  unsigned short* Klo = (unsigned short*)(ws + 1920000);
  float* Kn  = ws + 3840000;                               // [3.84M, 7.68M)
  float* Qn  = ws + 7680000;                               // [7.68M, 8.064M)
  unsigned short* Qhi = (unsigned short*)(ws + 8064000);
  unsigned short* Qlo = (unsigned short*)(ws + 8256000);
  float* part = ws + 8448000;                              // 3000*16*16

  lstm_kernel<<<250, 1024, 0, stream>>>(Xs, Wih, Whh, bih, bhh, H10);
  ln_kernel<<<7500, 256, 0, stream>>>(H10, ln_g, ln_b, 30000);
  proj_kernel<<<1875, 256, 0, stream>>>(H10, 0, 128, 30000, WK, Kn);
  proj_kernel<<<188, 256, 0, stream>>>(H10, 9 * 128, 1280, 3000, WQ, Qn);
  cvt_kernel<<<3750, 256, 0, stream>>>(Kn, Khi, Klo, 960000);
  cvt_kernel<<<375, 256, 0, stream>>>(Qn, Qhi, Qlo, 96000);
  {
    dim3 grid(94, SCHUNK);
    score_mfma<<<grid, 256, 0, stream>>>(Qhi, Qlo, Khi, Klo, tix, log_temp,
                                         lag_bias, part);
  }
  final_kernel<<<12, 256, 0, stream>>>(part, Qn, Kn, tix, log_temp, lag_bias,
                                       Xraw, W1, b1, W2, b2, W3, b3, outp);
}